// Round 6
// baseline (7976.206 us; speedup 1.0000x reference)
//
#include <hip/hip_runtime.h>
#include <hip/hip_bf16.h>

// NodeShuffle: kNN (K=16) edge-conv stack + max-pool + MLP + point shuffle.
// B=4, C=128, N=4096. ALL inputs and the output are FP32 (per reference
// setup_inputs/ output dtype; npz sizes confirm: in 8.33MB=fp32, out
// 15.39MB=fp32[4,128,8192]).
//
// ws layout (fp32 slots), total 9.3 MB:
//   p    [4][4096][128]  @ 0         (2,097,152 f32)
//   sq   [4][4096]       @ 2097152   (16,384 f32)
//   idx  [4][4096][16]   @ 2113536   (262,144 int32)

#define NN 4096
#define CCH 128
#define KNN 16

// ---------------------------------------------------------------- transpose
// x [B,C,N] f32 -> p [B,N,C] f32, LDS-tiled so both sides coalesce.
__global__ __launch_bounds__(256) void k_transpose(const float* __restrict__ x,
                                                   float* __restrict__ p) {
  __shared__ float tile[32][33];
  int b = blockIdx.z, n0 = blockIdx.x * 32, c0 = blockIdx.y * 32;
  int tx = threadIdx.x, ty = threadIdx.y;  // (32, 8)
  #pragma unroll
  for (int j = ty; j < 32; j += 8)
    tile[j][tx] = x[(size_t)(b * CCH + c0 + j) * NN + n0 + tx];
  __syncthreads();
  #pragma unroll
  for (int j = ty; j < 32; j += 8)
    p[(size_t)(b * NN + n0 + j) * CCH + c0 + tx] = tile[tx][j];
}

// ---------------------------------------------------------------- row norms
__global__ __launch_bounds__(64) void k_sqnorm(const float* __restrict__ p,
                                               float* __restrict__ sq) {
  int row = blockIdx.x, lane = threadIdx.x;
  float2 v = *(const float2*)(p + (size_t)row * CCH + lane * 2);
  float s = v.x * v.x + v.y * v.y;
  #pragma unroll
  for (int o = 32; o; o >>= 1) s += __shfl_down(s, o);
  if (lane == 0) sq[row] = s;
}

// ---------------------------------------------------------------- dist + top-16
// 2 query rows per block (256 thr), LDS = sd[2][4096] (32 KB) + q (1 KB).
// Phase 1: all 256 threads sweep the 4096 candidates, write fp32 distances.
// Phase 2: wave w in {0,1} extracts 16 minima of row w (argmin + knockout);
// waves 2-3 only join the uniform barriers. Only the neighbor SET matters
// downstream (max over K is permutation-invariant), so tie order vs
// jax.lax.top_k is irrelevant.
__global__ __launch_bounds__(256) void k_dist_topk(const float* __restrict__ p,
                                                   const float* __restrict__ sq,
                                                   int* __restrict__ idx) {
  __shared__ float q[2][128];
  __shared__ float sd[2][NN];
  __shared__ float sqr[2];
  int t = threadIdx.x;
  int row0 = blockIdx.x * 2;
  int b = row0 >> 12;
  int n0 = row0 & (NN - 1);
  const float* pb = p + (size_t)b * NN * CCH;
  const float* sqb = sq + (size_t)b * NN;
  for (int i = t; i < 2 * 128; i += 256)
    q[i >> 7][i & 127] = pb[(size_t)(n0 + (i >> 7)) * CCH + (i & 127)];
  if (t < 2) sqr[t] = sqb[n0 + t];
  __syncthreads();

  for (int m = t; m < NN; m += 256) {
    const float* pm = pb + (size_t)m * CCH;
    float d0 = 0.f, d1 = 0.f;
    #pragma unroll 8
    for (int c = 0; c < CCH; c += 4) {
      float4 v = *(const float4*)(pm + c);
      float4 a0 = *(const float4*)(&q[0][c]);
      float4 a1 = *(const float4*)(&q[1][c]);
      d0 += v.x * a0.x + v.y * a0.y + v.z * a0.z + v.w * a0.w;
      d1 += v.x * a1.x + v.y * a1.y + v.z * a1.z + v.w * a1.w;
    }
    float sm = sqb[m];
    sd[0][m] = sqr[0] + sm - 2.f * d0;
    sd[1][m] = sqr[1] + sm - 2.f * d1;
  }
  __syncthreads();

  int w = t >> 6, lane = t & 63;
  for (int k = 0; k < KNN; k++) {
    if (w < 2) {
      float* rowp = sd[w];
      float best = 3.4e38f;
      int bi = 0x7fffffff;
      for (int m = lane; m < NN; m += 64) {
        float v = rowp[m];
        if (v < best) { best = v; bi = m; }
      }
      #pragma unroll
      for (int o = 32; o; o >>= 1) {
        float ov = __shfl_xor(best, o);
        int oi = __shfl_xor(bi, o);
        if (ov < best || (ov == best && oi < bi)) { best = ov; bi = oi; }
      }
      if (lane == 0) {
        // fault guard: never emit an OOB index, even on pathological data
        if (bi < 0 || bi >= NN) bi = 0;
        idx[(size_t)(row0 + w) * KNN + k] = bi;
        rowp[bi] = 3.4e38f;
      }
    }
    __syncthreads();  // uniform: all 4 waves run exactly KNN iterations
  }
}

// ---------------------------------------------------------------- conv stack + final MLP + shuffle (fused)
// One point per block. feat[16][256] -> h1[16][128] -> h2[16][128] ->
// w3+b3 -> max over k -> hm[256] -> wm,bm -> out[b][co][2n+s] (fp32).
__global__ __launch_bounds__(256) void k_conv(
    const float* __restrict__ p, const int* __restrict__ idx,
    const float* __restrict__ w1, const float* __restrict__ b1,
    const float* __restrict__ g1, const float* __restrict__ be1,
    const float* __restrict__ m1, const float* __restrict__ v1,
    const float* __restrict__ w2, const float* __restrict__ b2,
    const float* __restrict__ g2, const float* __restrict__ be2,
    const float* __restrict__ m2, const float* __restrict__ v2,
    const float* __restrict__ w3, const float* __restrict__ b3,
    const float* __restrict__ wm, const float* __restrict__ bm,
    float* __restrict__ out) {
  __shared__ float feat[KNN][256];
  __shared__ float h1s[KNN][128];
  __shared__ float h2s[KNN][128];
  __shared__ float cen[128];
  __shared__ float hm[256];
  __shared__ int nidx[KNN];
  int t = threadIdx.x;
  int row = blockIdx.x;
  int b = row >> 12;
  int n = row & (NN - 1);
  const float* pb = p + (size_t)b * NN * CCH;
  if (t < KNN) {
    int v = idx[(size_t)row * KNN + t];
    nidx[t] = (v < 0 || v >= NN) ? 0 : v;  // fault guard
  }
  if (t < 128) cen[t] = pb[(size_t)n * CCH + t];
  __syncthreads();
  // gather edge features: cat(central - neigh, central)
  for (int e = t; e < KNN * 128; e += 256) {
    int k = e >> 7, c = e & 127;
    float cv = cen[c];
    feat[k][c] = cv - pb[(size_t)nidx[k] * CCH + c];
    feat[k][128 + c] = cv;
  }
  __syncthreads();
  // layer 1: 256 -> 128, BN + lrelu. thread -> (k = t>>4, 8 outputs o=og*8+i)
  {
    int k = t >> 4, og = t & 15;
    float acc[8] = {0, 0, 0, 0, 0, 0, 0, 0};
    for (int c = 0; c < 256; c += 4) {
      float4 f = *(const float4*)(&feat[k][c]);
      #pragma unroll
      for (int i = 0; i < 8; i++) {
        float4 wv = *(const float4*)(w1 + (size_t)(og * 8 + i) * 256 + c);
        acc[i] += f.x * wv.x + f.y * wv.y + f.z * wv.z + f.w * wv.w;
      }
    }
    #pragma unroll
    for (int i = 0; i < 8; i++) {
      int o = og * 8 + i;
      float y = acc[i] + b1[o];
      float sc = g1[o] / sqrtf(v1[o] + 1e-5f);
      y = (y - m1[o]) * sc + be1[o];
      h1s[k][o] = y >= 0.f ? y : 0.2f * y;
    }
  }
  __syncthreads();
  // layer 2: 128 -> 128, BN + lrelu
  {
    int k = t >> 4, og = t & 15;
    float acc[8] = {0, 0, 0, 0, 0, 0, 0, 0};
    for (int c = 0; c < 128; c += 4) {
      float4 f = *(const float4*)(&h1s[k][c]);
      #pragma unroll
      for (int i = 0; i < 8; i++) {
        float4 wv = *(const float4*)(w2 + (size_t)(og * 8 + i) * 128 + c);
        acc[i] += f.x * wv.x + f.y * wv.y + f.z * wv.z + f.w * wv.w;
      }
    }
    #pragma unroll
    for (int i = 0; i < 8; i++) {
      int o = og * 8 + i;
      float y = acc[i] + b2[o];
      float sc = g2[o] / sqrtf(v2[o] + 1e-5f);
      y = (y - m2[o]) * sc + be2[o];
      h2s[k][o] = y >= 0.f ? y : 0.2f * y;
    }
  }
  __syncthreads();
  // layer 3: 128 -> 256 (no BN), max over k. thread t owns channel t.
  {
    float acc[KNN];
    #pragma unroll
    for (int k = 0; k < KNN; k++) acc[k] = 0.f;
    for (int c = 0; c < 128; c += 4) {
      float4 wv = *(const float4*)(w3 + (size_t)t * 128 + c);
      #pragma unroll
      for (int k = 0; k < KNN; k++) {
        float4 h = *(const float4*)(&h2s[k][c]);
        acc[k] += h.x * wv.x + h.y * wv.y + h.z * wv.z + h.w * wv.w;
      }
    }
    float mx = acc[0];
    #pragma unroll
    for (int k = 1; k < KNN; k++) mx = fmaxf(mx, acc[k]);
    hm[t] = mx + b3[t];
  }
  __syncthreads();
  // final MLP (256->256) + point shuffle. thread t owns out channel t.
  {
    float acc = 0.f;
    for (int c = 0; c < 256; c += 4) {
      float4 wv = *(const float4*)(wm + (size_t)t * 256 + c);
      float4 h = *(const float4*)(&hm[c]);
      acc += h.x * wv.x + h.y * wv.y + h.z * wv.z + h.w * wv.w;
    }
    acc += bm[t];
    int co = t & 127, s = t >> 7;
    out[((size_t)(b * 128 + co)) * 8192 + 2 * n + s] = acc;
  }
}

extern "C" void kernel_launch(void* const* d_in, const int* in_sizes, int n_in,
                              void* d_out, int out_size, void* d_ws, size_t ws_size,
                              hipStream_t stream) {
  const float* x  = (const float*)d_in[0];
  const float* w1 = (const float*)d_in[1];
  const float* b1 = (const float*)d_in[2];
  const float* g1 = (const float*)d_in[3];
  const float* be1= (const float*)d_in[4];
  const float* m1 = (const float*)d_in[5];
  const float* v1 = (const float*)d_in[6];
  const float* w2 = (const float*)d_in[7];
  const float* b2 = (const float*)d_in[8];
  const float* g2 = (const float*)d_in[9];
  const float* be2= (const float*)d_in[10];
  const float* m2 = (const float*)d_in[11];
  const float* v2 = (const float*)d_in[12];
  const float* w3 = (const float*)d_in[13];
  const float* b3 = (const float*)d_in[14];
  const float* wm = (const float*)d_in[15];
  const float* bm = (const float*)d_in[16];

  float* ws = (float*)d_ws;
  float* p    = ws;
  float* sq   = ws + 2097152;
  int*   idx  = (int*)(ws + 2113536);
  float* out  = (float*)d_out;

  k_transpose<<<dim3(NN / 32, CCH / 32, 4), dim3(32, 8), 0, stream>>>(x, p);
  k_sqnorm<<<4 * NN, 64, 0, stream>>>(p, sq);
  k_dist_topk<<<4 * NN / 2, 256, 0, stream>>>(p, sq, idx);
  k_conv<<<4 * NN, 256, 0, stream>>>(p, idx, w1, b1, g1, be1, m1, v1,
                                     w2, b2, g2, be2, m2, v2, w3, b3,
                                     wm, bm, out);
}

// Round 7
// 2423.002 us; speedup vs baseline: 3.2919x; 3.2919x over previous
//
#include <hip/hip_runtime.h>
#include <hip/hip_bf16.h>

// NodeShuffle: kNN (K=16) edge-conv stack + max-pool + MLP + point shuffle.
// B=4, C=128, N=4096. All fp32.
//
// Key algebra: layer-1 over feat=[cen-neigh | cen] collapses to
//   h1[pt,k][o] = lrelu(bn1( T[pt][o] - U[nidx[pt,k]][o] ))
// where T = p @ (w1[:, :128]+w1[:, 128:])^T, U = p @ w1[:, :128]^T.
//
// ws layout (fp32 slots):
//   p     [16384][128] @ 0        (2,097,152)
//   sq    [16384]      @ 2097152  (16,384)
//   idx   [16384][16]  @ 2113536  (262,144 int32)
//   T     [16384][128] @ 2375680  (2,097,152)
//   U     [16384][128] @ 4472832  (2,097,152)
//   w1sT  [128][128]   @ 6569984  (16,384)
//   w1dT  [128][128]   @ 6586368  (16,384)
//   w2T   [128][128]   @ 6602752  (16,384)
//   w3T   [128][256]   @ 6619136  (32,768)
//   wmT   [256][256]   @ 6651904  (65,536)
// end 6,717,440 floats = 26.9 MB

#define NN 4096
#define CCH 128
#define KNN 16
#define BNEPS 1e-5f

__device__ __forceinline__ float lrelu(float y) { return y >= 0.f ? y : 0.2f * y; }

__device__ __forceinline__ void fma16(float4& a, const float4 h,
                                      const float4 w0, const float4 w1,
                                      const float4 w2, const float4 w3) {
  a.x += h.x * w0.x + h.y * w1.x + h.z * w2.x + h.w * w3.x;
  a.y += h.x * w0.y + h.y * w1.y + h.z * w2.y + h.w * w3.y;
  a.z += h.x * w0.z + h.y * w1.z + h.z * w2.z + h.w * w3.z;
  a.w += h.x * w0.w + h.y * w1.w + h.z * w2.w + h.w * w3.w;
}

// ---------------------------------------------------------------- transpose
__global__ __launch_bounds__(256) void k_transpose(const float* __restrict__ x,
                                                   float* __restrict__ p) {
  __shared__ float tile[32][33];
  int b = blockIdx.z, n0 = blockIdx.x * 32, c0 = blockIdx.y * 32;
  int tx = threadIdx.x, ty = threadIdx.y;  // (32, 8)
  #pragma unroll
  for (int j = ty; j < 32; j += 8)
    tile[j][tx] = x[(size_t)(b * CCH + c0 + j) * NN + n0 + tx];
  __syncthreads();
  #pragma unroll
  for (int j = ty; j < 32; j += 8)
    p[(size_t)(b * NN + n0 + j) * CCH + c0 + tx] = tile[tx][j];
}

// ---------------------------------------------------------------- weight prep (transpose + fold)
__global__ __launch_bounds__(256) void k_prepw(
    const float* __restrict__ w1, const float* __restrict__ w2,
    const float* __restrict__ w3, const float* __restrict__ wm,
    float* __restrict__ w1sT, float* __restrict__ w1dT,
    float* __restrict__ w2T, float* __restrict__ w3T, float* __restrict__ wmT) {
  int e = blockIdx.x * 256 + threadIdx.x;
  if (e < 16384) { int c = e >> 7, o = e & 127; w1sT[e] = w1[o * 256 + c] + w1[o * 256 + 128 + c]; return; }
  e -= 16384;
  if (e < 16384) { int c = e >> 7, o = e & 127; w1dT[e] = w1[o * 256 + c]; return; }
  e -= 16384;
  if (e < 16384) { int c = e >> 7, o = e & 127; w2T[e] = w2[o * 128 + c]; return; }
  e -= 16384;
  if (e < 32768) { int c = e >> 8, o = e & 255; w3T[e] = w3[o * 128 + c]; return; }
  e -= 32768;
  if (e < 65536) { int c = e >> 8, o = e & 255; wmT[e] = wm[o * 256 + c]; return; }
}

// ---------------------------------------------------------------- row norms
__global__ __launch_bounds__(64) void k_sqnorm(const float* __restrict__ p,
                                               float* __restrict__ sq) {
  int row = blockIdx.x, lane = threadIdx.x;
  float2 v = *(const float2*)(p + (size_t)row * CCH + lane * 2);
  float s = v.x * v.x + v.y * v.y;
  #pragma unroll
  for (int o = 32; o; o >>= 1) s += __shfl_down(s, o);
  if (lane == 0) sq[row] = s;
}

// ---------------------------------------------------------------- T,U GEMMs
// 64 p-rows per block; outer-product register tiling.
// thread: rl = t&7 (row-in-group), o0 = (t>>3)*4 (out quad); rows rl+8j.
__global__ __launch_bounds__(256, 4) void k_tu(const float* __restrict__ p,
                                               const float* __restrict__ w1sT,
                                               const float* __restrict__ w1dT,
                                               float* __restrict__ T,
                                               float* __restrict__ U) {
  __shared__ float pr[64 * 132];
  int t = threadIdx.x;
  int row0 = blockIdx.x * 64;
  for (int e = t; e < 64 * 128; e += 256) {
    int r = e >> 7, c = e & 127;
    pr[r * 132 + c] = p[(size_t)(row0 + r) * CCH + c];
  }
  __syncthreads();
  int rl = t & 7, o0 = (t >> 3) * 4;
  #pragma unroll
  for (int half = 0; half < 2; half++) {
    const float* W = half ? w1dT : w1sT;
    float* D = half ? U : T;
    float4 acc[8];
    #pragma unroll
    for (int j = 0; j < 8; j++) acc[j] = make_float4(0.f, 0.f, 0.f, 0.f);
    for (int c = 0; c < 128; c += 4) {
      float4 w0 = *(const float4*)(W + (size_t)(c + 0) * 128 + o0);
      float4 w1v = *(const float4*)(W + (size_t)(c + 1) * 128 + o0);
      float4 w2v = *(const float4*)(W + (size_t)(c + 2) * 128 + o0);
      float4 w3v = *(const float4*)(W + (size_t)(c + 3) * 128 + o0);
      #pragma unroll
      for (int j = 0; j < 8; j++) {
        float4 hv = *(const float4*)(pr + (rl + 8 * j) * 132 + c);
        fma16(acc[j], hv, w0, w1v, w2v, w3v);
      }
    }
    #pragma unroll
    for (int j = 0; j < 8; j++)
      *(float4*)(D + (size_t)(row0 + rl + 8 * j) * 128 + o0) = acc[j];
  }
}

// ---------------------------------------------------------------- dist + top-16
__global__ __launch_bounds__(256) void k_dist_topk(const float* __restrict__ p,
                                                   const float* __restrict__ sq,
                                                   int* __restrict__ idx) {
  __shared__ float q[2][128];
  __shared__ float sd[2][NN];
  __shared__ float sqr[2];
  int t = threadIdx.x;
  int row0 = blockIdx.x * 2;
  int b = row0 >> 12;
  int n0 = row0 & (NN - 1);
  const float* pb = p + (size_t)b * NN * CCH;
  const float* sqb = sq + (size_t)b * NN;
  for (int i = t; i < 2 * 128; i += 256)
    q[i >> 7][i & 127] = pb[(size_t)(n0 + (i >> 7)) * CCH + (i & 127)];
  if (t < 2) sqr[t] = sqb[n0 + t];
  __syncthreads();

  for (int m = t; m < NN; m += 256) {
    const float* pm = pb + (size_t)m * CCH;
    float d0 = 0.f, d1 = 0.f;
    #pragma unroll 8
    for (int c = 0; c < CCH; c += 4) {
      float4 v = *(const float4*)(pm + c);
      float4 a0 = *(const float4*)(&q[0][c]);
      float4 a1 = *(const float4*)(&q[1][c]);
      d0 += v.x * a0.x + v.y * a0.y + v.z * a0.z + v.w * a0.w;
      d1 += v.x * a1.x + v.y * a1.y + v.z * a1.z + v.w * a1.w;
    }
    float sm = sqb[m];
    sd[0][m] = sqr[0] + sm - 2.f * d0;
    sd[1][m] = sqr[1] + sm - 2.f * d1;
  }
  __syncthreads();

  int w = t >> 6, lane = t & 63;
  for (int k = 0; k < KNN; k++) {
    if (w < 2) {
      float* rowp = sd[w];
      float best = 3.4e38f;
      int bi = 0x7fffffff;
      for (int m = lane; m < NN; m += 64) {
        float v = rowp[m];
        if (v < best) { best = v; bi = m; }
      }
      #pragma unroll
      for (int o = 32; o; o >>= 1) {
        float ov = __shfl_xor(best, o);
        int oi = __shfl_xor(bi, o);
        if (ov < best || (ov == best && oi < bi)) { best = ov; bi = oi; }
      }
      if (lane == 0) {
        if (bi < 0 || bi >= NN) bi = 0;
        idx[(size_t)(row0 + w) * KNN + k] = bi;
        rowp[bi] = 3.4e38f;
      }
    }
    __syncthreads();
  }
}

// ---------------------------------------------------------------- conv stack (L1 gather + L2/L3 GEMM + max + final MLP)
// 4 points per block (64 edge rows). In-place h buffer [64][132].
__global__ __launch_bounds__(256, 4) void k_conv2(
    const float* __restrict__ T, const float* __restrict__ U,
    const int* __restrict__ idx,
    const float* __restrict__ b1, const float* __restrict__ g1,
    const float* __restrict__ be1, const float* __restrict__ m1, const float* __restrict__ v1,
    const float* __restrict__ w2T, const float* __restrict__ b2,
    const float* __restrict__ g2, const float* __restrict__ be2,
    const float* __restrict__ m2, const float* __restrict__ v2,
    const float* __restrict__ w3T, const float* __restrict__ b3,
    const float* __restrict__ wmT, const float* __restrict__ bm,
    float* __restrict__ out) {
  __shared__ float h[64 * 132];
  __shared__ float hmx[4 * 260];
  __shared__ int nidxs[64];
  int t = threadIdx.x;
  int pt0 = blockIdx.x * 4;  // global point base (0..16383)
  if (t < 64) {
    int v = idx[(size_t)pt0 * KNN + t];
    nidxs[t] = (v < 0 || v >= NN) ? 0 : v;
  }
  __syncthreads();

  // Phase A: h1 = lrelu(bn1(T[pt] - U[neighbor]))
  {
    int c = t & 127, half = t >> 7;
    float s1 = g1[c] / sqrtf(v1[c] + BNEPS);
    float C1 = be1[c] + (b1[c] - m1[c]) * s1;
    #pragma unroll 8
    for (int i = 0; i < 32; i++) {
      int r = half + 2 * i;
      int ptg = pt0 + (r >> 4);
      int bb = ptg >> 12;
      int nb = nidxs[r];
      float val = T[(size_t)ptg * 128 + c] - U[(size_t)((bb << 12) + nb) * 128 + c];
      h[r * 132 + c] = lrelu(val * s1 + C1);
    }
  }
  __syncthreads();

  int rl = t & 7, o0 = (t >> 3) * 4;

  // Phase B: L2 (128->128), BN+lrelu, in place.
  {
    float s2[4], C2[4];
    #pragma unroll
    for (int i = 0; i < 4; i++) {
      s2[i] = g2[o0 + i] / sqrtf(v2[o0 + i] + BNEPS);
      C2[i] = be2[o0 + i] + (b2[o0 + i] - m2[o0 + i]) * s2[i];
    }
    float4 acc[8];
    #pragma unroll
    for (int j = 0; j < 8; j++) acc[j] = make_float4(0.f, 0.f, 0.f, 0.f);
    for (int c = 0; c < 128; c += 4) {
      float4 w0 = *(const float4*)(w2T + (size_t)(c + 0) * 128 + o0);
      float4 w1v = *(const float4*)(w2T + (size_t)(c + 1) * 128 + o0);
      float4 w2v = *(const float4*)(w2T + (size_t)(c + 2) * 128 + o0);
      float4 w3v = *(const float4*)(w2T + (size_t)(c + 3) * 128 + o0);
      #pragma unroll
      for (int j = 0; j < 8; j++) {
        float4 hv = *(const float4*)(h + (rl + 8 * j) * 132 + c);
        fma16(acc[j], hv, w0, w1v, w2v, w3v);
      }
    }
    __syncthreads();  // all reads of h1 complete
    #pragma unroll
    for (int j = 0; j < 8; j++) {
      float4 y;
      y.x = lrelu(acc[j].x * s2[0] + C2[0]);
      y.y = lrelu(acc[j].y * s2[1] + C2[1]);
      y.z = lrelu(acc[j].z * s2[2] + C2[2]);
      y.w = lrelu(acc[j].w * s2[3] + C2[3]);
      *(float4*)(h + (rl + 8 * j) * 132 + o0) = y;
    }
  }
  __syncthreads();

  // Phase C: L3 (128->256) + max over k, two 128-wide halves.
  #pragma unroll
  for (int half = 0; half < 2; half++) {
    int ob = half * 128 + o0;
    float4 acc[8];
    #pragma unroll
    for (int j = 0; j < 8; j++) acc[j] = make_float4(0.f, 0.f, 0.f, 0.f);
    for (int c = 0; c < 128; c += 4) {
      float4 w0 = *(const float4*)(w3T + (size_t)(c + 0) * 256 + ob);
      float4 w1v = *(const float4*)(w3T + (size_t)(c + 1) * 256 + ob);
      float4 w2v = *(const float4*)(w3T + (size_t)(c + 2) * 256 + ob);
      float4 w3v = *(const float4*)(w3T + (size_t)(c + 3) * 256 + ob);
      #pragma unroll
      for (int j = 0; j < 8; j++) {
        float4 hv = *(const float4*)(h + (rl + 8 * j) * 132 + c);
        fma16(acc[j], hv, w0, w1v, w2v, w3v);
      }
    }
    #pragma unroll
    for (int ptl = 0; ptl < 4; ptl++) {
      float4 m;
      m.x = fmaxf(acc[2 * ptl].x, acc[2 * ptl + 1].x);
      m.y = fmaxf(acc[2 * ptl].y, acc[2 * ptl + 1].y);
      m.z = fmaxf(acc[2 * ptl].z, acc[2 * ptl + 1].z);
      m.w = fmaxf(acc[2 * ptl].w, acc[2 * ptl + 1].w);
      #pragma unroll
      for (int off = 1; off <= 4; off <<= 1) {
        m.x = fmaxf(m.x, __shfl_xor(m.x, off));
        m.y = fmaxf(m.y, __shfl_xor(m.y, off));
        m.z = fmaxf(m.z, __shfl_xor(m.z, off));
        m.w = fmaxf(m.w, __shfl_xor(m.w, off));
      }
      if (rl == 0) {
        float4 bv = *(const float4*)(b3 + ob);
        float4 o;
        o.x = m.x + bv.x; o.y = m.y + bv.y; o.z = m.z + bv.z; o.w = m.w + bv.w;
        *(float4*)(&hmx[ptl * 260 + ob]) = o;
      }
    }
  }
  __syncthreads();

  // Phase D: final MLP (256->256) + point shuffle.
  {
    int pt = t >> 6, oq = (t & 63) * 4;
    float4 acc = make_float4(0.f, 0.f, 0.f, 0.f);
    for (int c = 0; c < 256; c += 4) {
      float4 hv = *(const float4*)(&hmx[pt * 260 + c]);
      float4 w0 = *(const float4*)(wmT + (size_t)(c + 0) * 256 + oq);
      float4 w1v = *(const float4*)(wmT + (size_t)(c + 1) * 256 + oq);
      float4 w2v = *(const float4*)(wmT + (size_t)(c + 2) * 256 + oq);
      float4 w3v = *(const float4*)(wmT + (size_t)(c + 3) * 256 + oq);
      fma16(acc, hv, w0, w1v, w2v, w3v);
    }
    float4 bv = *(const float4*)(bm + oq);
    acc.x += bv.x; acc.y += bv.y; acc.z += bv.z; acc.w += bv.w;
    int ptg = pt0 + pt, bb = ptg >> 12, n = ptg & (NN - 1);
    float av[4] = {acc.x, acc.y, acc.z, acc.w};
    #pragma unroll
    for (int i = 0; i < 4; i++) {
      int o = oq + i;
      int co = o & 127, s = o >> 7;
      out[((size_t)(bb * 128 + co)) * 8192 + 2 * n + s] = av[i];
    }
  }
}

extern "C" void kernel_launch(void* const* d_in, const int* in_sizes, int n_in,
                              void* d_out, int out_size, void* d_ws, size_t ws_size,
                              hipStream_t stream) {
  const float* x  = (const float*)d_in[0];
  const float* w1 = (const float*)d_in[1];
  const float* b1 = (const float*)d_in[2];
  const float* g1 = (const float*)d_in[3];
  const float* be1= (const float*)d_in[4];
  const float* m1 = (const float*)d_in[5];
  const float* v1 = (const float*)d_in[6];
  const float* w2 = (const float*)d_in[7];
  const float* b2 = (const float*)d_in[8];
  const float* g2 = (const float*)d_in[9];
  const float* be2= (const float*)d_in[10];
  const float* m2 = (const float*)d_in[11];
  const float* v2 = (const float*)d_in[12];
  const float* w3 = (const float*)d_in[13];
  const float* b3 = (const float*)d_in[14];
  const float* wm = (const float*)d_in[15];
  const float* bm = (const float*)d_in[16];

  float* ws = (float*)d_ws;
  float* p     = ws;
  float* sq    = ws + 2097152;
  int*   idx   = (int*)(ws + 2113536);
  float* T     = ws + 2375680;
  float* U     = ws + 4472832;
  float* w1sT  = ws + 6569984;
  float* w1dT  = ws + 6586368;
  float* w2T   = ws + 6602752;
  float* w3T   = ws + 6619136;
  float* wmT   = ws + 6651904;
  float* out   = (float*)d_out;

  k_transpose<<<dim3(NN / 32, CCH / 32, 4), dim3(32, 8), 0, stream>>>(x, p);
  k_prepw<<<576, 256, 0, stream>>>(w1, w2, w3, wm, w1sT, w1dT, w2T, w3T, wmT);
  k_sqnorm<<<4 * NN, 64, 0, stream>>>(p, sq);
  k_tu<<<4 * NN / 64, 256, 0, stream>>>(p, w1sT, w1dT, T, U);
  k_dist_topk<<<4 * NN / 2, 256, 0, stream>>>(p, sq, idx);
  k_conv2<<<4 * NN / 4, 256, 0, stream>>>(T, U, idx,
                                          b1, g1, be1, m1, v1,
                                          w2T, b2, g2, be2, m2, v2,
                                          w3T, b3, wmT, bm, out);
}

// Round 16
// 1418.602 us; speedup vs baseline: 5.6226x; 1.7080x over previous
//
#include <hip/hip_runtime.h>
#include <hip/hip_bf16.h>

// NodeShuffle: kNN (K=16) edge-conv stack + max-pool + MLP + point shuffle.
// B=4, C=128, N=4096. All fp32.
//
// Layer-1 algebra: h1[pt,k][o] = lrelu(bn1( T[pt][o] - U[nidx[pt,k]][o] )),
// T = p @ (w1[:,:128]+w1[:,128:])^T, U = p @ w1[:,:128]^T.
// kNN ranking: argsort_m( sq[m] - 2*p[r].x[:,m] )  (sq[r] constant per row).
//
// ws layout (fp32 slots):
//   p     [16384][128] @ 0        (2,097,152)
//   sq    [16384]      @ 2097152  (16,384)
//   idx   [16384][16]  @ 2113536  (262,144 int32)
//   T     [16384][128] @ 2375680  (2,097,152)
//   U     [16384][128] @ 4472832  (2,097,152)
//   w1sT  [128][128]   @ 6569984  (16,384)
//   w1dT  [128][128]   @ 6586368  (16,384)
//   w2T   [128][128]   @ 6602752  (16,384)
//   w3T   [128][256]   @ 6619136  (32,768)
//   wmT   [256][256]   @ 6651904  (65,536)
//   dist  [4096][4096] @ 6717440  (16,777,216)  -- fast path only, per-batch
// fast-path end: 23,494,656 floats = 94.0 MB (runtime-checked vs ws_size)

#define NN 4096
#define CCH 128
#define KNN 16
#define BNEPS 1e-5f

__device__ __forceinline__ float lrelu(float y) { return y >= 0.f ? y : 0.2f * y; }

__device__ __forceinline__ void fma16(float4& a, const float4 h,
                                      const float4 w0, const float4 w1,
                                      const float4 w2, const float4 w3) {
  a.x += h.x * w0.x + h.y * w1.x + h.z * w2.x + h.w * w3.x;
  a.y += h.x * w0.y + h.y * w1.y + h.z * w2.y + h.w * w3.y;
  a.z += h.x * w0.z + h.y * w1.z + h.z * w2.z + h.w * w3.z;
  a.w += h.x * w0.w + h.y * w1.w + h.z * w2.w + h.w * w3.w;
}

// ---------------------------------------------------------------- transpose
__global__ __launch_bounds__(256) void k_transpose(const float* __restrict__ x,
                                                   float* __restrict__ p) {
  __shared__ float tile[32][33];
  int b = blockIdx.z, n0 = blockIdx.x * 32, c0 = blockIdx.y * 32;
  int tx = threadIdx.x, ty = threadIdx.y;  // (32, 8)
  #pragma unroll
  for (int j = ty; j < 32; j += 8)
    tile[j][tx] = x[(size_t)(b * CCH + c0 + j) * NN + n0 + tx];
  __syncthreads();
  #pragma unroll
  for (int j = ty; j < 32; j += 8)
    p[(size_t)(b * NN + n0 + j) * CCH + c0 + tx] = tile[tx][j];
}

// ---------------------------------------------------------------- weight prep
__global__ __launch_bounds__(256) void k_prepw(
    const float* __restrict__ w1, const float* __restrict__ w2,
    const float* __restrict__ w3, const float* __restrict__ wm,
    float* __restrict__ w1sT, float* __restrict__ w1dT,
    float* __restrict__ w2T, float* __restrict__ w3T, float* __restrict__ wmT) {
  int e = blockIdx.x * 256 + threadIdx.x;
  if (e < 16384) { int c = e >> 7, o = e & 127; w1sT[e] = w1[o * 256 + c] + w1[o * 256 + 128 + c]; return; }
  e -= 16384;
  if (e < 16384) { int c = e >> 7, o = e & 127; w1dT[e] = w1[o * 256 + c]; return; }
  e -= 16384;
  if (e < 16384) { int c = e >> 7, o = e & 127; w2T[e] = w2[o * 128 + c]; return; }
  e -= 16384;
  if (e < 32768) { int c = e >> 8, o = e & 255; w3T[e] = w3[o * 128 + c]; return; }
  e -= 32768;
  if (e < 65536) { int c = e >> 8, o = e & 255; wmT[e] = wm[o * 256 + c]; return; }
}

// ---------------------------------------------------------------- row norms
__global__ __launch_bounds__(64) void k_sqnorm(const float* __restrict__ p,
                                               float* __restrict__ sq) {
  int row = blockIdx.x, lane = threadIdx.x;
  float2 v = *(const float2*)(p + (size_t)row * CCH + lane * 2);
  float s = v.x * v.x + v.y * v.y;
  #pragma unroll
  for (int o = 32; o; o >>= 1) s += __shfl_down(s, o);
  if (lane == 0) sq[row] = s;
}

// ---------------------------------------------------------------- T,U GEMMs
__global__ __launch_bounds__(256, 4) void k_tu(const float* __restrict__ p,
                                               const float* __restrict__ w1sT,
                                               const float* __restrict__ w1dT,
                                               float* __restrict__ T,
                                               float* __restrict__ U) {
  __shared__ float pr[64 * 132];
  int t = threadIdx.x;
  int row0 = blockIdx.x * 64;
  for (int e = t; e < 64 * 128; e += 256) {
    int r = e >> 7, c = e & 127;
    pr[r * 132 + c] = p[(size_t)(row0 + r) * CCH + c];
  }
  __syncthreads();
  int rl = t & 7, o0 = (t >> 3) * 4;
  #pragma unroll
  for (int half = 0; half < 2; half++) {
    const float* W = half ? w1dT : w1sT;
    float* D = half ? U : T;
    float4 acc[8];
    #pragma unroll
    for (int j = 0; j < 8; j++) acc[j] = make_float4(0.f, 0.f, 0.f, 0.f);
    for (int c = 0; c < 128; c += 4) {
      float4 w0 = *(const float4*)(W + (size_t)(c + 0) * 128 + o0);
      float4 w1v = *(const float4*)(W + (size_t)(c + 1) * 128 + o0);
      float4 w2v = *(const float4*)(W + (size_t)(c + 2) * 128 + o0);
      float4 w3v = *(const float4*)(W + (size_t)(c + 3) * 128 + o0);
      #pragma unroll
      for (int j = 0; j < 8; j++) {
        float4 hv = *(const float4*)(pr + (rl + 8 * j) * 132 + c);
        fma16(acc[j], hv, w0, w1v, w2v, w3v);
      }
    }
    #pragma unroll
    for (int j = 0; j < 8; j++)
      *(float4*)(D + (size_t)(row0 + rl + 8 * j) * 128 + o0) = acc[j];
  }
}

// ---------------------------------------------------------------- dist GEMM (fast path)
// One batch per launch. Block: 64 query rows x 128 candidates.
// B-matrix is x[b] itself ([C][N] layout -> coalesced float4 along n).
// Writes rank-equivalent distance sq[m] - 2*dot to dist[r][m].
__global__ __launch_bounds__(256, 4) void k_dist(const float* __restrict__ p,
                                                 const float* __restrict__ x,
                                                 const float* __restrict__ sq,
                                                 float* __restrict__ dist,
                                                 int batch) {
  __shared__ float pr[64 * 132];
  int t = threadIdx.x;
  int row0 = blockIdx.y * 64;           // batch-local query row base
  int m0 = blockIdx.x * 128;            // candidate base
  const float* pb = p + (size_t)batch * NN * CCH;
  const float* xb = x + (size_t)batch * CCH * NN;
  for (int e = t; e < 64 * 128; e += 256) {
    int r = e >> 7, c = e & 127;
    pr[r * 132 + c] = pb[(size_t)(row0 + r) * CCH + c];
  }
  __syncthreads();
  int rl = t & 7, oq = (t >> 3) * 4;
  int m = m0 + oq;
  float4 acc[8];
  #pragma unroll
  for (int j = 0; j < 8; j++) acc[j] = make_float4(0.f, 0.f, 0.f, 0.f);
  for (int c = 0; c < 128; c += 4) {
    float4 w0 = *(const float4*)(xb + (size_t)(c + 0) * NN + m);
    float4 w1v = *(const float4*)(xb + (size_t)(c + 1) * NN + m);
    float4 w2v = *(const float4*)(xb + (size_t)(c + 2) * NN + m);
    float4 w3v = *(const float4*)(xb + (size_t)(c + 3) * NN + m);
    #pragma unroll
    for (int j = 0; j < 8; j++) {
      float4 hv = *(const float4*)(pr + (rl + 8 * j) * 132 + c);
      fma16(acc[j], hv, w0, w1v, w2v, w3v);
    }
  }
  float4 sqm = *(const float4*)(sq + (size_t)batch * NN + m);
  #pragma unroll
  for (int j = 0; j < 8; j++) {
    int r = row0 + rl + 8 * j;
    float4 d;
    d.x = sqm.x - 2.f * acc[j].x;
    d.y = sqm.y - 2.f * acc[j].y;
    d.z = sqm.z - 2.f * acc[j].z;
    d.w = sqm.w - 2.f * acc[j].w;
    *(float4*)(dist + (size_t)r * NN + m) = d;
  }
}

// ---------------------------------------------------------------- top-16 from dist (fast path)
__global__ __launch_bounds__(256) void k_topk(const float* __restrict__ dist,
                                              int* __restrict__ idx, int batch) {
  __shared__ float sd[2][NN];
  int t = threadIdx.x;
  int r0 = blockIdx.x * 2;  // batch-local
  for (int e = t; e < 2 * NN / 4; e += 256) {
    int r = e >> 10, c = (e & 1023) * 4;
    *(float4*)(&sd[r][c]) = *(const float4*)(dist + (size_t)(r0 + r) * NN + c);
  }
  __syncthreads();
  int w = t >> 6, lane = t & 63;
  for (int k = 0; k < KNN; k++) {
    if (w < 2) {
      float* rowp = sd[w];
      float best = 3.4e38f;
      int bi = 0x7fffffff;
      for (int m = lane; m < NN; m += 64) {
        float v = rowp[m];
        if (v < best) { best = v; bi = m; }
      }
      #pragma unroll
      for (int o = 32; o; o >>= 1) {
        float ov = __shfl_xor(best, o);
        int oi = __shfl_xor(bi, o);
        if (ov < best || (ov == best && oi < bi)) { best = ov; bi = oi; }
      }
      if (lane == 0) {
        if (bi < 0 || bi >= NN) bi = 0;
        idx[(size_t)(batch * NN + r0 + w) * KNN + k] = bi;
        rowp[bi] = 3.4e38f;
      }
    }
    __syncthreads();
  }
}

// ---------------------------------------------------------------- dist+topk fused (fallback, small ws)
__global__ __launch_bounds__(256) void k_dist_topk(const float* __restrict__ p,
                                                   const float* __restrict__ sq,
                                                   int* __restrict__ idx) {
  __shared__ float q[2][128];
  __shared__ float sd[2][NN];
  __shared__ float sqr[2];
  int t = threadIdx.x;
  int row0 = blockIdx.x * 2;
  int b = row0 >> 12;
  int n0 = row0 & (NN - 1);
  const float* pb = p + (size_t)b * NN * CCH;
  const float* sqb = sq + (size_t)b * NN;
  for (int i = t; i < 2 * 128; i += 256)
    q[i >> 7][i & 127] = pb[(size_t)(n0 + (i >> 7)) * CCH + (i & 127)];
  if (t < 2) sqr[t] = sqb[n0 + t];
  __syncthreads();

  for (int m = t; m < NN; m += 256) {
    const float* pm = pb + (size_t)m * CCH;
    float d0 = 0.f, d1 = 0.f;
    #pragma unroll 8
    for (int c = 0; c < CCH; c += 4) {
      float4 v = *(const float4*)(pm + c);
      float4 a0 = *(const float4*)(&q[0][c]);
      float4 a1 = *(const float4*)(&q[1][c]);
      d0 += v.x * a0.x + v.y * a0.y + v.z * a0.z + v.w * a0.w;
      d1 += v.x * a1.x + v.y * a1.y + v.z * a1.z + v.w * a1.w;
    }
    float sm = sqb[m];
    sd[0][m] = sqr[0] + sm - 2.f * d0;
    sd[1][m] = sqr[1] + sm - 2.f * d1;
  }
  __syncthreads();

  int w = t >> 6, lane = t & 63;
  for (int k = 0; k < KNN; k++) {
    if (w < 2) {
      float* rowp = sd[w];
      float best = 3.4e38f;
      int bi = 0x7fffffff;
      for (int m = lane; m < NN; m += 64) {
        float v = rowp[m];
        if (v < best) { best = v; bi = m; }
      }
      #pragma unroll
      for (int o = 32; o; o >>= 1) {
        float ov = __shfl_xor(best, o);
        int oi = __shfl_xor(bi, o);
        if (ov < best || (ov == best && oi < bi)) { best = ov; bi = oi; }
      }
      if (lane == 0) {
        if (bi < 0 || bi >= NN) bi = 0;
        idx[(size_t)(row0 + w) * KNN + k] = bi;
        rowp[bi] = 3.4e38f;
      }
    }
    __syncthreads();
  }
}

// ---------------------------------------------------------------- conv stack + final MLP (fused)
__global__ __launch_bounds__(256, 4) void k_conv2(
    const float* __restrict__ T, const float* __restrict__ U,
    const int* __restrict__ idx,
    const float* __restrict__ b1, const float* __restrict__ g1,
    const float* __restrict__ be1, const float* __restrict__ m1, const float* __restrict__ v1,
    const float* __restrict__ w2T, const float* __restrict__ b2,
    const float* __restrict__ g2, const float* __restrict__ be2,
    const float* __restrict__ m2, const float* __restrict__ v2,
    const float* __restrict__ w3T, const float* __restrict__ b3,
    const float* __restrict__ wmT, const float* __restrict__ bm,
    float* __restrict__ out) {
  __shared__ float h[64 * 132];
  __shared__ float hmx[4 * 260];
  __shared__ int nidxs[64];
  int t = threadIdx.x;
  int pt0 = blockIdx.x * 4;
  if (t < 64) {
    int v = idx[(size_t)pt0 * KNN + t];
    nidxs[t] = (v < 0 || v >= NN) ? 0 : v;
  }
  __syncthreads();

  // Phase A: h1 = lrelu(bn1(T[pt] - U[neighbor]))
  {
    int c = t & 127, half = t >> 7;
    float s1 = g1[c] / sqrtf(v1[c] + BNEPS);
    float C1 = be1[c] + (b1[c] - m1[c]) * s1;
    #pragma unroll 8
    for (int i = 0; i < 32; i++) {
      int r = half + 2 * i;
      int ptg = pt0 + (r >> 4);
      int bb = ptg >> 12;
      int nb = nidxs[r];
      float val = T[(size_t)ptg * 128 + c] - U[(size_t)((bb << 12) + nb) * 128 + c];
      h[r * 132 + c] = lrelu(val * s1 + C1);
    }
  }
  __syncthreads();

  int rl = t & 7, o0 = (t >> 3) * 4;

  // Phase B: L2 (128->128), BN+lrelu, in place.
  {
    float s2[4], C2[4];
    #pragma unroll
    for (int i = 0; i < 4; i++) {
      s2[i] = g2[o0 + i] / sqrtf(v2[o0 + i] + BNEPS);
      C2[i] = be2[o0 + i] + (b2[o0 + i] - m2[o0 + i]) * s2[i];
    }
    float4 acc[8];
    #pragma unroll
    for (int j = 0; j < 8; j++) acc[j] = make_float4(0.f, 0.f, 0.f, 0.f);
    for (int c = 0; c < 128; c += 4) {
      float4 w0 = *(const float4*)(w2T + (size_t)(c + 0) * 128 + o0);
      float4 w1v = *(const float4*)(w2T + (size_t)(c + 1) * 128 + o0);
      float4 w2v = *(const float4*)(w2T + (size_t)(c + 2) * 128 + o0);
      float4 w3v = *(const float4*)(w2T + (size_t)(c + 3) * 128 + o0);
      #pragma unroll
      for (int j = 0; j < 8; j++) {
        float4 hv = *(const float4*)(h + (rl + 8 * j) * 132 + c);
        fma16(acc[j], hv, w0, w1v, w2v, w3v);
      }
    }
    __syncthreads();
    #pragma unroll
    for (int j = 0; j < 8; j++) {
      float4 y;
      y.x = lrelu(acc[j].x * s2[0] + C2[0]);
      y.y = lrelu(acc[j].y * s2[1] + C2[1]);
      y.z = lrelu(acc[j].z * s2[2] + C2[2]);
      y.w = lrelu(acc[j].w * s2[3] + C2[3]);
      *(float4*)(h + (rl + 8 * j) * 132 + o0) = y;
    }
  }
  __syncthreads();

  // Phase C: L3 (128->256) + max over k.
  #pragma unroll
  for (int half = 0; half < 2; half++) {
    int ob = half * 128 + o0;
    float4 acc[8];
    #pragma unroll
    for (int j = 0; j < 8; j++) acc[j] = make_float4(0.f, 0.f, 0.f, 0.f);
    for (int c = 0; c < 128; c += 4) {
      float4 w0 = *(const float4*)(w3T + (size_t)(c + 0) * 256 + ob);
      float4 w1v = *(const float4*)(w3T + (size_t)(c + 1) * 256 + ob);
      float4 w2v = *(const float4*)(w3T + (size_t)(c + 2) * 256 + ob);
      float4 w3v = *(const float4*)(w3T + (size_t)(c + 3) * 256 + ob);
      #pragma unroll
      for (int j = 0; j < 8; j++) {
        float4 hv = *(const float4*)(h + (rl + 8 * j) * 132 + c);
        fma16(acc[j], hv, w0, w1v, w2v, w3v);
      }
    }
    #pragma unroll
    for (int ptl = 0; ptl < 4; ptl++) {
      float4 m;
      m.x = fmaxf(acc[2 * ptl].x, acc[2 * ptl + 1].x);
      m.y = fmaxf(acc[2 * ptl].y, acc[2 * ptl + 1].y);
      m.z = fmaxf(acc[2 * ptl].z, acc[2 * ptl + 1].z);
      m.w = fmaxf(acc[2 * ptl].w, acc[2 * ptl + 1].w);
      #pragma unroll
      for (int off = 1; off <= 4; off <<= 1) {
        m.x = fmaxf(m.x, __shfl_xor(m.x, off));
        m.y = fmaxf(m.y, __shfl_xor(m.y, off));
        m.z = fmaxf(m.z, __shfl_xor(m.z, off));
        m.w = fmaxf(m.w, __shfl_xor(m.w, off));
      }
      if (rl == 0) {
        float4 bv = *(const float4*)(b3 + ob);
        float4 o;
        o.x = m.x + bv.x; o.y = m.y + bv.y; o.z = m.z + bv.z; o.w = m.w + bv.w;
        *(float4*)(&hmx[ptl * 260 + ob]) = o;
      }
    }
  }
  __syncthreads();

  // Phase D: final MLP (256->256) + point shuffle.
  {
    int pt = t >> 6, oq = (t & 63) * 4;
    float4 acc = make_float4(0.f, 0.f, 0.f, 0.f);
    for (int c = 0; c < 256; c += 4) {
      float4 hv = *(const float4*)(&hmx[pt * 260 + c]);
      float4 w0 = *(const float4*)(wmT + (size_t)(c + 0) * 256 + oq);
      float4 w1v = *(const float4*)(wmT + (size_t)(c + 1) * 256 + oq);
      float4 w2v = *(const float4*)(wmT + (size_t)(c + 2) * 256 + oq);
      float4 w3v = *(const float4*)(wmT + (size_t)(c + 3) * 256 + oq);
      fma16(acc, hv, w0, w1v, w2v, w3v);
    }
    float4 bv = *(const float4*)(bm + oq);
    acc.x += bv.x; acc.y += bv.y; acc.z += bv.z; acc.w += bv.w;
    int ptg = pt0 + pt, bb = ptg >> 12, n = ptg & (NN - 1);
    float av[4] = {acc.x, acc.y, acc.z, acc.w};
    #pragma unroll
    for (int i = 0; i < 4; i++) {
      int o = oq + i;
      int co = o & 127, s = o >> 7;
      out[((size_t)(bb * 128 + co)) * 8192 + 2 * n + s] = av[i];
    }
  }
}

extern "C" void kernel_launch(void* const* d_in, const int* in_sizes, int n_in,
                              void* d_out, int out_size, void* d_ws, size_t ws_size,
                              hipStream_t stream) {
  const float* x  = (const float*)d_in[0];
  const float* w1 = (const float*)d_in[1];
  const float* b1 = (const float*)d_in[2];
  const float* g1 = (const float*)d_in[3];
  const float* be1= (const float*)d_in[4];
  const float* m1 = (const float*)d_in[5];
  const float* v1 = (const float*)d_in[6];
  const float* w2 = (const float*)d_in[7];
  const float* b2 = (const float*)d_in[8];
  const float* g2 = (const float*)d_in[9];
  const float* be2= (const float*)d_in[10];
  const float* m2 = (const float*)d_in[11];
  const float* v2 = (const float*)d_in[12];
  const float* w3 = (const float*)d_in[13];
  const float* b3 = (const float*)d_in[14];
  const float* wm = (const float*)d_in[15];
  const float* bm = (const float*)d_in[16];

  float* ws = (float*)d_ws;
  float* p     = ws;
  float* sq    = ws + 2097152;
  int*   idx   = (int*)(ws + 2113536);
  float* T     = ws + 2375680;
  float* U     = ws + 4472832;
  float* w1sT  = ws + 6569984;
  float* w1dT  = ws + 6586368;
  float* w2T   = ws + 6602752;
  float* w3T   = ws + 6619136;
  float* wmT   = ws + 6651904;
  float* dist  = ws + 6717440;
  float* out   = (float*)d_out;

  // ws_size is constant across calls -> branch is deterministic (graph-safe).
  bool fast = ws_size >= (size_t)(6717440 + 16777216) * 4;

  k_transpose<<<dim3(NN / 32, CCH / 32, 4), dim3(32, 8), 0, stream>>>(x, p);
  k_prepw<<<576, 256, 0, stream>>>(w1, w2, w3, wm, w1sT, w1dT, w2T, w3T, wmT);
  k_sqnorm<<<4 * NN, 64, 0, stream>>>(p, sq);
  k_tu<<<4 * NN / 64, 256, 0, stream>>>(p, w1sT, w1dT, T, U);
  if (fast) {
    for (int b = 0; b < 4; b++) {
      k_dist<<<dim3(NN / 128, NN / 64), 256, 0, stream>>>(p, x, sq, dist, b);
      k_topk<<<NN / 2, 256, 0, stream>>>(dist, idx, b);
    }
  } else {
    k_dist_topk<<<4 * NN / 2, 256, 0, stream>>>(p, sq, idx);
  }
  k_conv2<<<4 * NN / 4, 256, 0, stream>>>(T, U, idx,
                                          b1, g1, be1, m1, v1,
                                          w2T, b2, g2, be2, m2, v2,
                                          w3T, b3, wmT, bm, out);
}